// Round 4
// baseline (186.059 us; speedup 1.0000x reference)
//
#include <hip/hip_runtime.h>
#include <math.h>

#define NN 4096
#define DD 256
#define HH 4
#define SPLIT 8
#define BM 64
#define BK 64
#define STR 72   // old-path LDS stride

typedef short short8 __attribute__((ext_vector_type(8)));
typedef float float4v __attribute__((ext_vector_type(4)));

__device__ __forceinline__ unsigned short f2bf(float f) {
  unsigned u = __float_as_uint(f);
  u += 0x7FFF + ((u >> 16) & 1);   // RNE
  return (unsigned short)(u >> 16);
}
__device__ __forceinline__ unsigned int f2bf_pk(float a, float b) {
  // packed bf16 pair: low half = rne(a), high half = rne(b)
  unsigned ua = __float_as_uint(a); ua += 0x7FFF + ((ua >> 16) & 1);
  unsigned ub = __float_as_uint(b); ub += 0x7FFF + ((ub >> 16) & 1);
  return __builtin_amdgcn_perm(ub, ua, 0x07060302);
}

// ---------------- zero hp (old-path atomic fallback only) ----------------
__global__ void k_zero(float* __restrict__ hp) {
  int idx = blockIdx.x * 256 + threadIdx.x;
  ((float4*)hp)[idx] = make_float4(0.f, 0.f, 0.f, 0.f);
}

// ---------------- hbfT[d][j] = bf16(x[j][d]*cw+cb)  (64x64 transpose tiles) ----------------
__global__ __launch_bounds__(256) void k_prep(const float* __restrict__ x,
                                              const float* __restrict__ cwp,
                                              const float* __restrict__ cbp,
                                              unsigned short* __restrict__ hbfT) {
  __shared__ float t[64][65];
  const int j0 = (blockIdx.x & 63) * 64;
  const int d0 = (blockIdx.x >> 6) * 64;
  const int tid = threadIdx.x;
  const float cw = cwp[0], cb = cbp[0];
  const int r = tid >> 4, c4 = tid & 15;
#pragma unroll
  for (int p = 0; p < 4; p++) {
    const int jj = p * 16 + r;
    const float4 v = *(const float4*)(x + (size_t)(j0 + jj) * DD + d0 + c4 * 4);
    t[jj][c4 * 4 + 0] = v.x * cw + cb;
    t[jj][c4 * 4 + 1] = v.y * cw + cb;
    t[jj][c4 * 4 + 2] = v.z * cw + cb;
    t[jj][c4 * 4 + 3] = v.w * cw + cb;
  }
  __syncthreads();
  const int jj = tid & 63, dq = tid >> 6;
#pragma unroll
  for (int k = 0; k < 16; k++) {
    const int dd = k * 4 + dq;
    hbfT[(size_t)(d0 + dd) * NN + j0 + jj] = f2bf(t[jj][dd]);
  }
}

// ---------------- s1, s2, and E = exp(s2) ----------------
__global__ void k_scores(const float* __restrict__ x, const float* __restrict__ a,
                         const float* __restrict__ cwp, const float* __restrict__ cbp,
                         float* __restrict__ s1, float* __restrict__ s2,
                         float* __restrict__ s2e) {
  const int lane = threadIdx.x & 63;
  const int wave = threadIdx.x >> 6;
  const int node = blockIdx.x * 4 + wave;
  const float cw = cwp[0], cb = cbp[0];
  const float4 xv = *(const float4*)(x + (size_t)node * DD + lane * 4);
  float4 hv;
  hv.x = xv.x * cw + cb; hv.y = xv.y * cw + cb;
  hv.z = xv.z * cw + cb; hv.w = xv.w * cw + cb;
  float p1[HH], p2[HH];
#pragma unroll
  for (int h = 0; h < HH; h++) {
    const float4 a1 = *(const float4*)(a + h * 512 + lane * 4);
    const float4 a2 = *(const float4*)(a + h * 512 + 256 + lane * 4);
    p1[h] = hv.x * a1.x + hv.y * a1.y + hv.z * a1.z + hv.w * a1.w;
    p2[h] = hv.x * a2.x + hv.y * a2.y + hv.z * a2.z + hv.w * a2.w;
  }
#pragma unroll
  for (int off = 32; off; off >>= 1) {
#pragma unroll
    for (int h = 0; h < HH; h++) {
      p1[h] += __shfl_xor(p1[h], off);
      p2[h] += __shfl_xor(p2[h], off);
    }
  }
  if (lane == 0) {
#pragma unroll
    for (int h = 0; h < HH; h++) {
      s1[h * NN + node] = p1[h];
      s2[h * NN + node] = p2[h];
      s2e[h * NN + node] = __expf(p2[h]);
    }
  }
}

// ---------------- M[h] = max_j s2[h][j] ----------------
__global__ void k_maxs2(const float* __restrict__ s2, float* __restrict__ M) {
  const int h = blockIdx.x;
  float m = -1e30f;
  for (int j = threadIdx.x; j < NN; j += 256) m = fmaxf(m, s2[h * NN + j]);
#pragma unroll
  for (int off = 32; off; off >>= 1) m = fmaxf(m, __shfl_xor(m, off));
  __shared__ float red[4];
  const int lane = threadIdx.x & 63, wave = threadIdx.x >> 6;
  if (lane == 0) red[wave] = m;
  __syncthreads();
  if (threadIdx.x == 0)
    M[h] = fmaxf(fmaxf(red[0], red[1]), fmaxf(red[2], red[3]));
}

// ========== fused Z + W, separable exp: t>0 -> no exp, t<=0 -> one exp ==========
__global__ __launch_bounds__(256) void k_zw(
    const int* __restrict__ adj, const float* __restrict__ s1g,
    const float* __restrict__ s2e, const float* __restrict__ Mb,
    unsigned short* __restrict__ Wm) {
  __shared__ unsigned int sP[HH][NN / 2];   // 32 KB packed bf16 pairs
  __shared__ float red[4][HH];
  __shared__ float sZi[HH];

  const int i = blockIdx.x;
  const int tid = threadIdx.x;
  float Rp[HH], RpRB[HH], Cc[HH], z[HH];
#pragma unroll
  for (int h = 0; h < HH; h++) {
    const float s1v = s1g[h * NN + i];
    const float t = s1v + Mb[h];
    const float B = t > 0.f ? t : __expf(t) - 1.f;
    Rp[h] = __expf(s1v);
    RpRB[h] = __expf(s1v - B);
    Cc[h] = __expf(-1.f - B);
    z[h] = 0.f;
  }
  const int4* arow = (const int4*)(adj + (size_t)i * NN);
  for (int j4 = tid; j4 < NN / 4; j4 += 256) {
    const int4 av = arow[j4];
    const bool m0 = av.x > 0, m1 = av.y > 0, m2 = av.z > 0, m3 = av.w > 0;
#pragma unroll
    for (int h = 0; h < HH; h++) {
      const float4 E = *(const float4*)(s2e + h * NN + j4 * 4);
      float u, p0, p1, p2, p3;
      u = Rp[h] * E.x; p0 = u > 1.f ? RpRB[h] * E.x : Cc[h] * __expf(u);
      u = Rp[h] * E.y; p1 = u > 1.f ? RpRB[h] * E.y : Cc[h] * __expf(u);
      u = Rp[h] * E.z; p2 = u > 1.f ? RpRB[h] * E.z : Cc[h] * __expf(u);
      u = Rp[h] * E.w; p3 = u > 1.f ? RpRB[h] * E.w : Cc[h] * __expf(u);
      p0 = m0 ? p0 : 0.f; p1 = m1 ? p1 : 0.f;
      p2 = m2 ? p2 : 0.f; p3 = m3 ? p3 : 0.f;
      z[h] += (p0 + p1) + (p2 + p3);
      sP[h][j4 * 2] = f2bf_pk(p0, p1);
      sP[h][j4 * 2 + 1] = f2bf_pk(p2, p3);
    }
  }
#pragma unroll
  for (int h = 0; h < HH; h++) {
#pragma unroll
    for (int off = 32; off; off >>= 1) z[h] += __shfl_xor(z[h], off);
  }
  const int lane = tid & 63, wave = tid >> 6;
  if (lane == 0) {
#pragma unroll
    for (int h = 0; h < HH; h++) red[wave][h] = z[h];
  }
  __syncthreads();
  if (tid < HH) {
    const float zt = red[0][tid] + red[1][tid] + red[2][tid] + red[3][tid];
    sZi[tid] = zt > 0.f ? 0.25f / zt : 0.f;
  }
  __syncthreads();
  float Zi[HH];
#pragma unroll
  for (int h = 0; h < HH; h++) Zi[h] = sZi[h];

  unsigned int* wrow = (unsigned int*)(Wm + (size_t)i * NN);
  for (int j4 = tid; j4 < NN / 4; j4 += 256) {
    float w0 = 0.f, w1 = 0.f, w2 = 0.f, w3 = 0.f;
#pragma unroll
    for (int h = 0; h < HH; h++) {
      const unsigned int pa = sP[h][j4 * 2];
      const unsigned int pb = sP[h][j4 * 2 + 1];
      w0 += __uint_as_float(pa << 16) * Zi[h];
      w1 += __uint_as_float(pa & 0xffff0000u) * Zi[h];
      w2 += __uint_as_float(pb << 16) * Zi[h];
      w3 += __uint_as_float(pb & 0xffff0000u) * Zi[h];
    }
    wrow[j4 * 2] = f2bf_pk(w0, w1);
    wrow[j4 * 2 + 1] = f2bf_pk(w2, w3);
  }
}

// ========== barrier-free MFMA GEMM: fragments loaded straight from global ==========
__global__ __launch_bounds__(256) void k_gemm(
    const unsigned short* __restrict__ Wm, const unsigned short* __restrict__ hbfT,
    float* __restrict__ hpOut) {
  const int tid = threadIdx.x;
  const int w = tid >> 6, lane = tid & 63;
  const int m16 = lane & 15, q = lane >> 4;
  const int rb = blockIdx.x >> 3, sp = blockIdx.x & 7;
  const int i0 = rb * BM;
  const int jlo = sp * (NN / SPLIT);

  // per-lane fragment base pointers: A rows i0+it*16+m16, B rows w*64+dt*16+m16
  const unsigned short* Ab = Wm + (size_t)(i0 + m16) * NN + jlo + q * 8;
  const unsigned short* Bb = hbfT + (size_t)(w * 64 + m16) * NN + jlo + q * 8;

  float4v acc[4][4];
#pragma unroll
  for (int a = 0; a < 4; a++)
#pragma unroll
    for (int b = 0; b < 4; b++) acc[a][b] = (float4v)0.f;

#pragma unroll 2
  for (int kt = 0; kt < (NN / SPLIT) / BK; kt++) {
    short8 aF[2][4], bF[2][4];
#pragma unroll
    for (int ks = 0; ks < 2; ks++)
#pragma unroll
      for (int it = 0; it < 4; it++)
        aF[ks][it] = *(const short8*)(Ab + (size_t)it * 16 * NN + kt * BK + ks * 32);
#pragma unroll
    for (int ks = 0; ks < 2; ks++)
#pragma unroll
      for (int dt = 0; dt < 4; dt++)
        bF[ks][dt] = *(const short8*)(Bb + (size_t)dt * 16 * NN + kt * BK + ks * 32);
#pragma unroll
    for (int ks = 0; ks < 2; ks++)
#pragma unroll
      for (int it = 0; it < 4; it++)
#pragma unroll
        for (int dt = 0; dt < 4; dt++)
          acc[it][dt] = __builtin_amdgcn_mfma_f32_16x16x32_bf16(aF[ks][it], bF[ks][dt], acc[it][dt], 0, 0, 0);
  }

  float* base = hpOut + (size_t)sp * NN * DD;
#pragma unroll
  for (int it = 0; it < 4; it++)
#pragma unroll
    for (int dt = 0; dt < 4; dt++) {
      const int d = w * 64 + dt * 16 + m16;
#pragma unroll
      for (int rg = 0; rg < 4; rg++) {
        const int i = i0 + it * 16 + q * 4 + rg;
        base[(size_t)i * DD + d] = acc[it][dt][rg];
      }
    }
}

// ========== OLD PATH fallback kernels (round-2, proven) ==========
__global__ void k_z(const int* __restrict__ adj, const float* __restrict__ s1,
                    const float* __restrict__ s2, const float* __restrict__ Mb,
                    float* __restrict__ Bb, float* __restrict__ Zb) {
  const int i = blockIdx.x;
  float s1v[HH], Bv[HH], z[HH];
#pragma unroll
  for (int h = 0; h < HH; h++) {
    s1v[h] = s1[h * NN + i];
    const float t = s1v[h] + Mb[h];
    Bv[h] = t > 0.f ? t : __expf(t) - 1.f;
    z[h] = 0.f;
  }
  const int4* arow = (const int4*)(adj + (size_t)i * NN);
  for (int j4 = threadIdx.x; j4 < NN / 4; j4 += 256) {
    const int4 av = arow[j4];
#pragma unroll
    for (int h = 0; h < HH; h++) {
      const float4 sv = *(const float4*)(s2 + h * NN + j4 * 4);
      float t, e;
      t = s1v[h] + sv.x; e = t > 0.f ? t : __expf(t) - 1.f;
      z[h] += av.x > 0 ? __expf(e - Bv[h]) : 0.f;
      t = s1v[h] + sv.y; e = t > 0.f ? t : __expf(t) - 1.f;
      z[h] += av.y > 0 ? __expf(e - Bv[h]) : 0.f;
      t = s1v[h] + sv.z; e = t > 0.f ? t : __expf(t) - 1.f;
      z[h] += av.z > 0 ? __expf(e - Bv[h]) : 0.f;
      t = s1v[h] + sv.w; e = t > 0.f ? t : __expf(t) - 1.f;
      z[h] += av.w > 0 ? __expf(e - Bv[h]) : 0.f;
    }
  }
#pragma unroll
  for (int h = 0; h < HH; h++) {
#pragma unroll
    for (int off = 32; off; off >>= 1) z[h] += __shfl_xor(z[h], off);
  }
  __shared__ float red[4][HH];
  const int lane = threadIdx.x & 63, wave = threadIdx.x >> 6;
  if (lane == 0) {
#pragma unroll
    for (int h = 0; h < HH; h++) red[wave][h] = z[h];
  }
  __syncthreads();
  if (threadIdx.x == 0) {
#pragma unroll
    for (int h = 0; h < HH; h++) {
      Zb[h * NN + i] = red[0][h] + red[1][h] + red[2][h] + red[3][h];
      Bb[h * NN + i] = Bv[h];
    }
  }
}

__global__ __launch_bounds__(256) void k_agg_fused(
    const int* __restrict__ adj, const unsigned short* __restrict__ hbfT,
    const float* __restrict__ s1, const float* __restrict__ s2,
    const float* __restrict__ Bb, const float* __restrict__ Zb,
    float* __restrict__ hpOut, int useSplit) {
  __shared__ unsigned short sW[BM * STR];
  __shared__ unsigned short sH[DD * STR];
  __shared__ float sS1[HH][BM], sB[HH][BM], sZi[HH][BM], ss2[HH][BK];

  const int tid = threadIdx.x;
  const int w = tid >> 6, lane = tid & 63;
  const int m16 = lane & 15, q = lane >> 4;
  const int rb = blockIdx.x >> 3, sp = blockIdx.x & 7;
  const int i0 = rb * BM;
  const int jlo = sp * (NN / SPLIT);

  {
    const float zv = Zb[w * NN + i0 + lane];
    sS1[w][lane] = s1[w * NN + i0 + lane];
    sB[w][lane] = Bb[w * NN + i0 + lane];
    sZi[w][lane] = zv > 0.f ? 0.25f / zv : 0.f;
  }

  float4v acc[4][4];
#pragma unroll
  for (int a = 0; a < 4; a++)
#pragma unroll
    for (int b = 0; b < 4; b++) acc[a][b] = (float4v)0.f;

  for (int kt = 0; kt < (NN / SPLIT) / BK; kt++) {
    const int j0 = jlo + kt * BK;
    __syncthreads();
    ss2[w][lane] = s2[w * NN + j0 + lane];
    {
      const int dbase = tid >> 3, part = tid & 7;
#pragma unroll
      for (int r = 0; r < 8; r++) {
        const int d = dbase + r * 32;
        const float4 v = *(const float4*)(hbfT + (size_t)d * NN + j0 + part * 8);
        *(float4*)(sH + d * STR + part * 8) = v;
      }
    }
    __syncthreads();
    {
      const int jj = lane;
#pragma unroll
      for (int r = 0; r < 16; r++) {
        const int ii = r * 4 + w;
        const int av = adj[(size_t)(i0 + ii) * NN + j0 + jj];
        float wsum = 0.f;
#pragma unroll
        for (int h = 0; h < HH; h++) {
          const float tv = sS1[h][ii] + ss2[h][jj];
          const float e = tv > 0.f ? tv : __expf(tv) - 1.f;
          wsum += __expf(e - sB[h][ii]) * sZi[h][ii];
        }
        sW[ii * STR + jj] = av > 0 ? f2bf(wsum) : (unsigned short)0;
      }
    }
    __syncthreads();
#pragma unroll
    for (int ks = 0; ks < 2; ks++) {
      const int kb = ks * 32 + q * 8;
      short8 aF[4], bF[4];
#pragma unroll
      for (int it = 0; it < 4; it++)
        aF[it] = *(const short8*)(sW + (it * 16 + m16) * STR + kb);
#pragma unroll
      for (int dt = 0; dt < 4; dt++)
        bF[dt] = *(const short8*)(sH + (w * 64 + dt * 16 + m16) * STR + kb);
#pragma unroll
      for (int it = 0; it < 4; it++)
#pragma unroll
        for (int dt = 0; dt < 4; dt++)
          acc[it][dt] = __builtin_amdgcn_mfma_f32_16x16x32_bf16(aF[it], bF[dt], acc[it][dt], 0, 0, 0);
    }
  }

  if (useSplit) {
    float* base = hpOut + (size_t)sp * NN * DD;
#pragma unroll
    for (int it = 0; it < 4; it++)
#pragma unroll
      for (int dt = 0; dt < 4; dt++) {
        const int d = w * 64 + dt * 16 + m16;
#pragma unroll
        for (int rg = 0; rg < 4; rg++) {
          const int i = i0 + it * 16 + q * 4 + rg;
          base[(size_t)i * DD + d] = acc[it][dt][rg];
        }
      }
  } else {
#pragma unroll
    for (int it = 0; it < 4; it++)
#pragma unroll
      for (int dt = 0; dt < 4; dt++) {
        const int d = w * 64 + dt * 16 + m16;
#pragma unroll
        for (int rg = 0; rg < 4; rg++) {
          const int i = i0 + it * 16 + q * 4 + rg;
          atomicAdd(&hpOut[(size_t)i * DD + d], acc[it][dt][rg]);
        }
      }
  }
}

// ---------------- epilogue ----------------
__global__ void k_epi(const float* __restrict__ hp, int nsplit,
                      const float* __restrict__ x, const float* __restrict__ cwp,
                      const float* __restrict__ cbp, const float* __restrict__ bias,
                      float* __restrict__ out) {
  const int lane = threadIdx.x & 63, wave = threadIdx.x >> 6;
  const int i = blockIdx.x * 4 + wave;
  const float cw = cwp[0], cb = cbp[0];
  float o[4];
  float ss = 0.f;
#pragma unroll
  for (int k = 0; k < 4; k++) {
    const int d = lane + 64 * k;
    float pv = 0.f;
    for (int s = 0; s < nsplit; s++)
      pv += hp[(size_t)s * NN * DD + (size_t)i * DD + d];
    const float hv = x[(size_t)i * DD + d] * cw + cb;
    float v = 0.5f * pv + 0.5f * hv;
    v = v > 0.f ? v : expm1f(v);
    o[k] = v;
    ss += v * v;
  }
#pragma unroll
  for (int off = 32; off; off >>= 1) ss += __shfl_xor(ss, off);
  const float inv = 1.f / fmaxf(sqrtf(ss), 1e-12f);
#pragma unroll
  for (int k = 0; k < 4; k++) {
    const int d = lane + 64 * k;
    out[(size_t)i * DD + d] = o[k] * inv + bias[d];
  }
}

extern "C" void kernel_launch(void* const* d_in, const int* in_sizes, int n_in,
                              void* d_out, int out_size, void* d_ws, size_t ws_size,
                              hipStream_t stream) {
  const float* x = (const float*)d_in[0];
  const int* adj = (const int*)d_in[1];
  const float* cw = (const float*)d_in[2];
  const float* cb = (const float*)d_in[3];
  const float* a = (const float*)d_in[4];
  const float* bias = (const float*)d_in[5];
  float* out = (float*)d_out;
  float* ws = (float*)d_ws;

  // New-path layout (float units): s1 | s2 | s2e | Mb | hbfT | Wm | hp
  const size_t newNeed = (size_t)(16384 * 3 + 256 + 524288 + 8388608 + 8388608) * 4;

  if (ws_size >= newNeed) {
    float* s1 = ws;
    float* s2 = ws + 16384;
    float* s2e = ws + 32768;
    float* Mb = ws + 49152;
    unsigned short* hbfT = (unsigned short*)(ws + 49408);
    unsigned short* Wm = (unsigned short*)(ws + 49408 + 524288);
    float* hp = ws + 49408 + 524288 + 8388608;

    hipLaunchKernelGGL(k_prep, dim3(256), dim3(256), 0, stream, x, cw, cb, hbfT);
    hipLaunchKernelGGL(k_scores, dim3(1024), dim3(256), 0, stream, x, a, cw, cb, s1, s2, s2e);
    hipLaunchKernelGGL(k_maxs2, dim3(HH), dim3(256), 0, stream, s2, Mb);
    hipLaunchKernelGGL(k_zw, dim3(NN), dim3(256), 0, stream, adj, s1, s2e, Mb, Wm);
    hipLaunchKernelGGL(k_gemm, dim3((NN / BM) * SPLIT), dim3(256), 0, stream, Wm, hbfT, hp);
    hipLaunchKernelGGL(k_epi, dim3(1024), dim3(256), 0, stream, hp, SPLIT, x, cw, cb, bias, out);
  } else {
    // round-2 fallback
    float* s1 = ws;
    float* s2 = ws + 16384;
    float* Zb = ws + 32768;
    float* Bb = ws + 49152;
    float* Mb = ws + 65536;
    unsigned short* hbfT = (unsigned short*)(ws + 65792);
    float* hp = ws + 65792 + 524288;

    const size_t needSplit = (size_t)(65792 + 524288 + SPLIT * NN * DD) * 4;
    const int useSplit = (ws_size >= needSplit) ? 1 : 0;
    const int nsplit = useSplit ? SPLIT : 1;

    if (!useSplit) hipLaunchKernelGGL(k_zero, dim3(1024), dim3(256), 0, stream, hp);
    hipLaunchKernelGGL(k_prep, dim3(256), dim3(256), 0, stream, x, cw, cb, hbfT);
    hipLaunchKernelGGL(k_scores, dim3(1024), dim3(256), 0, stream, x, a, cw, cb, s1, s2, Bb);
    hipLaunchKernelGGL(k_maxs2, dim3(HH), dim3(256), 0, stream, s2, Mb);
    hipLaunchKernelGGL(k_z, dim3(NN), dim3(256), 0, stream, adj, s1, s2, Mb, Bb, Zb);
    hipLaunchKernelGGL(k_agg_fused, dim3((NN / BM) * SPLIT), dim3(256), 0, stream,
                       adj, hbfT, s1, s2, Bb, Zb, hp, useSplit);
    hipLaunchKernelGGL(k_epi, dim3(1024), dim3(256), 0, stream, hp, nsplit, x, cw, cb, bias, out);
  }
}